// Round 2
// 690.257 us; speedup vs baseline: 1.0328x; 1.0328x over previous
//
#include <hip/hip_runtime.h>
#include <cstdint>

typedef _Float16 f16;
typedef __attribute__((ext_vector_type(8))) _Float16 half8;
typedef __attribute__((ext_vector_type(4))) float floatx4;

#define NB      40000
#define M_TOTAL 80000
#define DIN     1024
#define LDIM    512
#define NBLK    1250   // 64-row blocks
#define BPB     625    // fused blocks per batch
#define NCHUNK  16     // reduce stage-1 chunks per batch
#define RCHUNK  40     // fused blocks per chunk (15*40 + 25 = 625)

// ---------------- kernel 0: pack weights into MFMA B-fragment order --------
// packedF[((kb*512 + n)*4 + lq)*8 + j] = f16(Wf[(kb*32 + lq*8 + j)*512 + n]), kb<32
// packedAB: cols c<768 interleave a/g per 16: d=(c>>5)*16+(c&15), type=(c>>4)&1
__global__ void k_prep(const float* __restrict__ Wf, const float* __restrict__ Wa,
                       const float* __restrict__ Wb,
                       f16* __restrict__ packedF, f16* __restrict__ packedAB)
{
    const int gid = blockIdx.x * 256 + threadIdx.x;
    if (gid < 65536) {
        const int lq = gid & 3, n = (gid >> 2) & 511, kb = gid >> 11;
        const int kbase = kb * 32 + lq * 8;
        half8 v;
        #pragma unroll
        for (int j = 0; j < 8; ++j) v[j] = (f16)Wf[(kbase + j) * 512 + n];
        *(half8*)&packedF[(long)gid * 8] = v;
    } else if (gid < 65536 + 49152) {
        const int g = gid - 65536;
        const int kb = g / 3072;
        const int rem = g - kb * 3072;
        const int c = rem >> 2, lq = rem & 3;
        const int d = ((c >> 5) << 4) + (c & 15);
        const int type = (c >> 4) & 1;
        const float* src = type ? Wb : Wa;
        const int kbase = kb * 32 + lq * 8;
        half8 v;
        #pragma unroll
        for (int j = 0; j < 8; ++j) v[j] = (f16)src[(kbase + j) * 384 + d];
        *(half8*)&packedAB[(long)g * 8] = v;
    }
}

__device__ inline float fast_sigmoid(float xx) { return 1.0f / (1.0f + __expf(-xx)); }
__device__ inline float fast_tanh(float xx) {
    float e = __expf(-2.0f * fabsf(xx));
    float r = (1.0f - e) / (1.0f + e);
    return xx >= 0.0f ? r : -r;
}

// ---------------- kernel 1: fully fused per-64-row pipeline -----------------
// x-tile -> h (LDS) -> a/g -> s -> e^s -> partial pooled sums. h never hits HBM.
// No softmax max-subtraction: e^s ratio is shift-invariant; |s|<=||Wc||_1 ~ 22.
// LDS = Hs(64x512 f16, XOR-swz) + As(64x128 f16, XOR-swz) = 81920 B exactly
//     -> 2 blocks/CU. wbuf aliases As (As dead when wbuf live).
// Swizzle: f16 col' = col ^ ((row&7)<<3)  (16B-granular, bijective per row,
// uniform 8-lanes-per-bank-slot for every b128 access pattern here).
__global__ __launch_bounds__(512, 4) void k_fused(
    const float* __restrict__ x, const f16* __restrict__ packedF,
    const f16* __restrict__ packedAB,
    const float* __restrict__ bf, const float* __restrict__ ba,
    const float* __restrict__ bb, const float* __restrict__ Wc,
    float* __restrict__ partial_pool, float* __restrict__ partial_denom)
{
    __shared__ __align__(16) f16 Hs[64][512];
    __shared__ __align__(16) f16 As[64][128];
    float* wbuf = (float*)&As[0][0];          // alias: first 256B of As

    const int tid = threadIdx.x;
    const int w = tid >> 6, lane = tid & 63, lr = lane & 15, lq = lane >> 4;
    const long row0 = (long)blockIdx.x * 64;
    const int sr = tid >> 3;                  // stage row 0..63
    const int sc = (tid & 7) << 4;            // stage col 0..112 (f16 units)
    const int swzw = (sr & 7) << 3;           // write-side XOR
    const int swzr = (lr & 7) << 3;           // read-side XOR (row&7 == lr&7)
    const float* xp = x + (row0 + sr) * DIN + sc;

    // ---------------- phase 1: h-tile = relu(x @ Wf + bf), BK=128 ----------
    floatx4 acc[4][4] = {};
    float4 xr0 = *(const float4*)xp;
    float4 xr1 = *(const float4*)(xp + 4);
    float4 xr2 = *(const float4*)(xp + 8);
    float4 xr3 = *(const float4*)(xp + 12);
    for (int kt = 0; kt < 8; ++kt) {
        if (kt) __syncthreads();              // all readers of As done
        {
            half8 v0, v1;
            v0[0]=(f16)xr0.x; v0[1]=(f16)xr0.y; v0[2]=(f16)xr0.z; v0[3]=(f16)xr0.w;
            v0[4]=(f16)xr1.x; v0[5]=(f16)xr1.y; v0[6]=(f16)xr1.z; v0[7]=(f16)xr1.w;
            v1[0]=(f16)xr2.x; v1[1]=(f16)xr2.y; v1[2]=(f16)xr2.z; v1[3]=(f16)xr2.w;
            v1[4]=(f16)xr3.x; v1[5]=(f16)xr3.y; v1[6]=(f16)xr3.z; v1[7]=(f16)xr3.w;
            *(half8*)&As[sr][sc ^ swzw] = v0;
            *(half8*)&As[sr][(sc + 8) ^ swzw] = v1;
        }
        __syncthreads();                      // stage visible
        if (kt < 7) {                         // prefetch lands during MFMAs
            const float* q = xp + (kt + 1) * 128;
            xr0 = *(const float4*)q;
            xr1 = *(const float4*)(q + 4);
            xr2 = *(const float4*)(q + 8);
            xr3 = *(const float4*)(q + 12);
        }
        #pragma unroll
        for (int kq = 0; kq < 4; ++kq) {
            const int kb = kt * 4 + kq;
            half8 bfr[4];
            #pragma unroll
            for (int tj = 0; tj < 4; ++tj)
                bfr[tj] = *(const half8*)&packedF[(long)((kb * 512 + w * 64 + tj * 16 + lr) << 5) + lq * 8];
            half8 af[4];
            #pragma unroll
            for (int ti = 0; ti < 4; ++ti)
                af[ti] = *(const half8*)&As[ti * 16 + lr][(kq * 32 + lq * 8) ^ swzr];
            #pragma unroll
            for (int tj = 0; tj < 4; ++tj)
                #pragma unroll
                for (int ti = 0; ti < 4; ++ti)
                    acc[ti][tj] = __builtin_amdgcn_mfma_f32_16x16x32_f16(af[ti], bfr[tj], acc[ti][tj], 0, 0, 0);
        }
    }
    // epilogue -> Hs (LDS only). C/D: col=lr, row=lq*4+r
    #pragma unroll
    for (int tj = 0; tj < 4; ++tj) {
        const int col = w * 64 + tj * 16 + lr;
        const float bias = bf[col];
        #pragma unroll
        for (int ti = 0; ti < 4; ++ti)
            #pragma unroll
            for (int r = 0; r < 4; ++r) {
                const int row = ti * 16 + lq * 4 + r;
                Hs[row][col ^ ((row & 7) << 3)] = (f16)fmaxf(acc[ti][tj][r] + bias, 0.0f);
            }
    }
    __syncthreads();                          // Hs complete; As fully consumed
    if (tid < 64) wbuf[tid] = 0.0f;           // safe: aliases dead As
    __syncthreads();                          // publish zeros

    // ---------------- phase 2: a/g GEMM from LDS (no barriers) ------------
    floatx4 acc2[4][6] = {};
    for (int kb = 0; kb < 16; ++kb) {         // K=512
        half8 af[4];
        #pragma unroll
        for (int ti = 0; ti < 4; ++ti)
            af[ti] = *(const half8*)&Hs[ti * 16 + lr][(kb * 32 + lq * 8) ^ swzr];
        #pragma unroll
        for (int tj = 0; tj < 6; ++tj) {
            half8 bfr = *(const half8*)&packedAB[(long)((kb * 768 + w * 96 + tj * 16 + lr) << 5) + lq * 8];
            #pragma unroll
            for (int ti = 0; ti < 4; ++ti)
                acc2[ti][tj] = __builtin_amdgcn_mfma_f32_16x16x32_f16(af[ti], bfr, acc2[ti][tj], 0, 0, 0);
        }
    }
    // epilogue: s_row += sum_d tanh(a+ba)*sigmoid(g+bb)*Wc[d]   (bc cancels)
    float sp[4][4] = {};
    #pragma unroll
    for (int u = 0; u < 3; ++u) {
        const int d = w * 48 + u * 16 + lr;
        const float biasA = ba[d], biasB = bb[d], wcv = Wc[d];
        #pragma unroll
        for (int ti = 0; ti < 4; ++ti)
            #pragma unroll
            for (int r = 0; r < 4; ++r) {
                const float av = fast_tanh(acc2[ti][2 * u][r] + biasA);
                const float gv = fast_sigmoid(acc2[ti][2 * u + 1][r] + biasB);
                sp[ti][r] += av * gv * wcv;
            }
    }
    #pragma unroll
    for (int m = 1; m < 16; m <<= 1)
        #pragma unroll
        for (int ti = 0; ti < 4; ++ti)
            #pragma unroll
            for (int r = 0; r < 4; ++r)
                sp[ti][r] += __shfl_xor(sp[ti][r], m, 64);
    if (lr == 0) {
        #pragma unroll
        for (int ti = 0; ti < 4; ++ti)
            #pragma unroll
            for (int r = 0; r < 4; ++r)
                atomicAdd(&wbuf[ti * 16 + lq * 4 + r], sp[ti][r]);
    }
    __syncthreads();
    if (tid < 64) wbuf[tid] = __expf(wbuf[tid]);   // attention weights (unnormalized)
    __syncthreads();

    // ---------------- phase 3: partial pooled sums ------------------------
    {
        const int c = tid;                     // 512 threads <-> 512 cols
        float pacc = 0.0f;
        #pragma unroll 8
        for (int n = 0; n < 64; ++n)
            pacc += wbuf[n] * (float)Hs[n][c ^ ((n & 7) << 3)];
        partial_pool[(long)blockIdx.x * 512 + c] = pacc;
    }
    if (w == 0) {                              // wave 0: denom partial
        float dsum = wbuf[lane];
        #pragma unroll
        for (int o = 32; o > 0; o >>= 1) dsum += __shfl_xor(dsum, o, 64);
        if (lane == 0) partial_denom[blockIdx.x] = dsum;
    }
}

// ---------------- kernel 2a: stage-1 reduce (32 blocks, was 2) --------------
__global__ __launch_bounds__(512) void k_reduce1(
    const float* __restrict__ pp, const float* __restrict__ pd,
    float* __restrict__ pp2, float* __restrict__ pd2)
{
    __shared__ float dsh[8];
    const int b = blockIdx.x >> 4, chunk = blockIdx.x & 15;
    const int tid = threadIdx.x;
    const int r0 = chunk * RCHUNK;
    const int rows = (BPB - r0 < RCHUNK) ? (BPB - r0) : RCHUNK;
    const float* base = pp + ((long)b * BPB + r0) * 512 + tid;
    float acc = 0.0f;
    for (int i = 0; i < rows; ++i) acc += base[(long)i * 512];
    pp2[((long)b * NCHUNK + chunk) * 512 + tid] = acc;
    float d = 0.0f;
    for (int i = tid; i < rows; i += 512) d += pd[b * BPB + r0 + i];
    #pragma unroll
    for (int o = 32; o > 0; o >>= 1) d += __shfl_xor(d, o, 64);
    if ((tid & 63) == 0) dsh[tid >> 6] = d;
    __syncthreads();
    if (tid == 0)
        pd2[b * NCHUNK + chunk] = dsh[0] + dsh[1] + dsh[2] + dsh[3]
                                + dsh[4] + dsh[5] + dsh[6] + dsh[7];
}

// ---------------- kernel 2b: final reduce + logits --------------------------
__global__ __launch_bounds__(512) void k_reduce2(
    const float* __restrict__ pp2, const float* __restrict__ pd2,
    const float* __restrict__ Wcls, const float* __restrict__ bcls,
    float* __restrict__ out)
{
    __shared__ float pooled[512];
    __shared__ float dsh[8];
    const int b = blockIdx.x, tid = threadIdx.x;
    float acc = 0.0f;
    const float* base = pp2 + (long)b * NCHUNK * 512 + tid;
    #pragma unroll
    for (int i = 0; i < NCHUNK; ++i) acc += base[i * 512];
    pooled[tid] = acc;
    float d = (tid < NCHUNK) ? pd2[b * NCHUNK + tid] : 0.0f;
    #pragma unroll
    for (int o = 32; o > 0; o >>= 1) d += __shfl_xor(d, o, 64);
    if ((tid & 63) == 0) dsh[tid >> 6] = d;
    __syncthreads();
    const float denom = dsh[0] + dsh[1] + dsh[2] + dsh[3] + dsh[4] + dsh[5] + dsh[6] + dsh[7];
    if (tid < 128) {                           // 2 waves: cls = wave
        const int cls = tid >> 6, ln = tid & 63;
        float sum = 0.0f;
        #pragma unroll
        for (int t = 0; t < 8; ++t)
            sum += pooled[t * 64 + ln] * Wcls[(t * 64 + ln) * 2 + cls];
        #pragma unroll
        for (int o = 32; o > 0; o >>= 1) sum += __shfl_xor(sum, o, 64);
        if (ln == 0) out[b * 2 + cls] = sum / denom + bcls[cls];
    }
}

// ---------------- launch ----------------
extern "C" void kernel_launch(void* const* d_in, const int* in_sizes, int n_in,
                              void* d_out, int out_size, void* d_ws, size_t ws_size,
                              hipStream_t stream)
{
    const float* x    = (const float*)d_in[0];
    const float* Wf   = (const float*)d_in[1];
    const float* bf   = (const float*)d_in[2];
    const float* Wa   = (const float*)d_in[3];
    const float* ba   = (const float*)d_in[4];
    const float* Wb   = (const float*)d_in[5];
    const float* bb   = (const float*)d_in[6];
    const float* Wc   = (const float*)d_in[7];
    // d_in[8] = bc: constant shift over n, cancels in the softmax ratio -> unused
    const float* Wcls = (const float*)d_in[9];
    const float* bcls = (const float*)d_in[10];
    float* out = (float*)d_out;

    // workspace layout (16B aligned), total ~4.4 MB
    char* w = (char*)d_ws;
    f16*   packedF  = (f16*)(w);                   // 1,048,576
    f16*   packedAB = (f16*)(w + 1048576);         //   786,432
    float* ppool    = (float*)(w + 1835008);       // 2,560,000 (1250 x 512 fp32)
    float* pdenom   = (float*)(w + 4395008);       //     5,000
    // stage-2 buffers alias packedF (dead after k_fused; re-filled by k_prep
    // at the start of every launch, so graph replay is safe)
    float* pp2      = (float*)(w);                 //    65,536 (2 x 16 x 512)
    float* pd2      = (float*)(w + 65536);         //       128

    k_prep   <<<448, 256, 0, stream>>>(Wf, Wa, Wb, packedF, packedAB);
    k_fused  <<<NBLK, 512, 0, stream>>>(x, packedF, packedAB, bf, ba, bb, Wc, ppool, pdenom);
    k_reduce1<<<32, 512, 0, stream>>>(ppool, pdenom, pp2, pd2);
    k_reduce2<<<2, 512, 0, stream>>>(pp2, pd2, Wcls, bcls, out);
}